// Round 1
// baseline (409.163 us; speedup 1.0000x reference)
//
#include <hip/hip_runtime.h>
#include <math.h>

// ToHyperSphere: x (B=65536, D=1024) fp32 -> out (B, D) fp32
// out[0]   = sqrt(sum x^2)                        (r)
// out[j]   = acos(x[j-1]/suffix_norm[j-1]), j=1..D-2
// out[D-1] = x[D-1] < 0 ? 2pi - phi[D-2] : phi[D-2]
// suffix_norm[j] = sqrt(sum_{k>=j} x[k]^2)
//
// One 256-thread block per row, 4 consecutive elements per thread (float4).
// Suffix scan: thread-local (4 elems) -> wave inclusive suffix scan
// (__shfl_down, guarded, wave=64) -> cross-wave via 4-float LDS.
// Output is phi shifted by +1: thread t needs x[4t-1]; fetched with
// __shfl_up(v.w,1) + LDS patch at the 3 wave boundaries. Stores are
// aligned float4 -> fully coalesced.

#define D_DIM 1024
#define TPB 256  // 4 elements per thread

__global__ __launch_bounds__(TPB) void tohypersphere_kernel(
    const float* __restrict__ x, float* __restrict__ out) {
    const int t = threadIdx.x;
    const int lane = t & 63;
    const int wave = t >> 6;
    const size_t row_off = (size_t)blockIdx.x * D_DIM;

    const float4 v = ((const float4*)(x + row_off))[t];

    // thread-local suffix sums of squares (element 4t+k)
    float s3 = v.w * v.w;
    float s2 = fmaf(v.z, v.z, s3);
    float s1 = fmaf(v.y, v.y, s2);
    float s0 = fmaf(v.x, v.x, s1);  // sum over this thread's 4 elems

    // wave-level inclusive suffix scan of thread totals (64-lane wave)
    float tot = s0;
#pragma unroll
    for (int off = 1; off < 64; off <<= 1) {
        float n = __shfl_down(tot, off, 64);
        if (lane + off < 64) tot += n;
    }

    __shared__ float wave_tot[4];  // per-wave total = lane 0's inclusive value
    __shared__ float edge_xw[4];   // last element (v.w) of each wave's lane 63
    if (lane == 0) wave_tot[wave] = tot;
    if (lane == 63) edge_xw[wave] = v.w;
    __syncthreads();

    float after = 0.0f;
#pragma unroll
    for (int w = 0; w < 4; ++w)
        if (w > wave) after += wave_tot[w];

    const float incl = tot + after;   // suffix[4t] = sum_{k>=4t} x[k]^2
    const float excl = incl - s0;     // sum over elements strictly after 4t+3

    // previous thread's last element x[4t-1]
    float xw_prev = __shfl_up(v.w, 1, 64);
    if (lane == 0 && wave > 0) xw_prev = edge_xw[wave - 1];

    const float suf0 = incl;          // suffix[4t]
    const float suf1 = s1 + excl;     // suffix[4t+1]
    const float suf2 = s2 + excl;     // suffix[4t+2]

    // phi(num, den) = acos(clamp(num/sqrt(den)))
    auto ang = [](float num, float den) {
        float r = num * rsqrtf(den);
        r = fminf(1.0f, fmaxf(-1.0f, r));
        return acosf(r);
    };

    float o0, o1, o2, o3;
    o1 = ang(v.x, suf0);                                   // phi[4t]   -> out[4t+1]
    o2 = ang(v.y, suf1);                                   // phi[4t+1] -> out[4t+2]
    o3 = ang(v.z, suf2);                                   // phi[4t+2] -> out[4t+3]
    if (t == 0) {
        o0 = sqrtf(incl);                                  // r -> out[0]
    } else {
        // phi[4t-1]: suffix[4t-1] = x[4t-1]^2 + suffix[4t]
        o0 = ang(xw_prev, fmaf(xw_prev, xw_prev, incl));
    }
    if (t == TPB - 1) {
        // out[D-1]: sign-adjusted phi[D-2] (o3 here is phi[1022])
        if (v.w < 0.0f) o3 = 6.283185307179586476f - o3;
    }

    ((float4*)(out + row_off))[t] = make_float4(o0, o1, o2, o3);
}

extern "C" void kernel_launch(void* const* d_in, const int* in_sizes, int n_in,
                              void* d_out, int out_size, void* d_ws, size_t ws_size,
                              hipStream_t stream) {
    const float* x = (const float*)d_in[0];
    float* out = (float*)d_out;
    const int B = in_sizes[0] / D_DIM;  // 65536
    tohypersphere_kernel<<<B, TPB, 0, stream>>>(x, out);
}